// Round 8
// baseline (275.586 us; speedup 1.0000x reference)
//
#include <hip/hip_runtime.h>

// 2-layer fused LSTM + linear head.  B=8192, T=128, D=32, H=64, gates=256.
// R8 = R6 structure (512 thr / 8 waves, BT=16, grid 512, 1 barrier/step,
// x prefetch) + POLYNOMIAL exp2: hw v_exp_f32 measured ~33cy/wave64 (83% of
// VALU-pipe demand); poly (med3 clamp + rndne + 5 FMA + int-bit 2^n) ~22cy
// of full-rate ops.  Rel err 2.4e-6 (deg-5 Taylor on [-1/2,1/2]) << f16 noise.
// Wave wv owns h in [8wv,8wv+8) as 2 gate-interleaved row-tiles:
//   D element r of lane (bl,kg) = gate r of h = hbase+kg (all 4 gates/lane).
// log2e folded into weights (i,f,o x1.4427; g x2.8854); merged-rcp gate math:
//   5 exp2 + 2 rcp per element.

#define TT  128
#define DIN 32
#define BT  16
#define L2E 1.44269504088896340736f

typedef _Float16 h8 __attribute__((ext_vector_type(8)));
typedef __fp16   p2 __attribute__((ext_vector_type(2)));
typedef float    f4 __attribute__((ext_vector_type(4)));

__device__ __forceinline__ h8 cvt8s(const float* p, float s) {
    float4 a = *(const float4*)p;
    float4 b = *(const float4*)(p + 4);
    union { h8 v; p2 q[4]; } u;
    u.q[0] = __builtin_amdgcn_cvt_pkrtz(a.x * s, a.y * s);
    u.q[1] = __builtin_amdgcn_cvt_pkrtz(a.z * s, a.w * s);
    u.q[2] = __builtin_amdgcn_cvt_pkrtz(b.x * s, b.y * s);
    u.q[3] = __builtin_amdgcn_cvt_pkrtz(b.z * s, b.w * s);
    return u.v;
}

__device__ __forceinline__ h8 pack8(const float4& a, const float4& b) {
    union { h8 v; p2 q[4]; } u;
    u.q[0] = __builtin_amdgcn_cvt_pkrtz(a.x, a.y);
    u.q[1] = __builtin_amdgcn_cvt_pkrtz(a.z, a.w);
    u.q[2] = __builtin_amdgcn_cvt_pkrtz(b.x, b.y);
    u.q[3] = __builtin_amdgcn_cvt_pkrtz(b.z, b.w);
    return u.v;
}

// exp2 via full-rate VALU: clamp, round-nearest range reduction, deg-5 Taylor
// on [-0.5,0.5], scale by 2^n built as integer bits.  ~22cy vs ~33cy hw trans.
__device__ __forceinline__ float fexp2(float x) {
    x = __builtin_amdgcn_fmed3f(x, -126.f, 126.f);
    float n = __builtin_rintf(x);
    float f = x - n;
    float p = 0.0013333558146f;
    p = __builtin_fmaf(p, f, 0.0096181291076f);
    p = __builtin_fmaf(p, f, 0.0555041086648f);
    p = __builtin_fmaf(p, f, 0.2402265069591f);
    p = __builtin_fmaf(p, f, 0.6931471805599f);
    p = __builtin_fmaf(p, f, 1.0f);
    int ni = (int)n;
    float s = __int_as_float((ni << 23) + 0x3f800000);
    return p * s;
}

// acc = {yi', yf', yg'(2x-scaled), yo'} (log2e pre-folded); updates c, returns h.
__device__ __forceinline__ float elem(const f4& acc, float& c) {
    float Ei = fexp2(-acc[0]);
    float Ef = fexp2(-acc[1]);
    float Eg = fexp2(-acc[2]);
    float Eo = fexp2(-acc[3]);
    float a = 1.f + Ei, b = 1.f + Eg, d = 1.f + Ef;
    float P = a * b;
    float N = c * P + (1.f - Eg) * d;
    c = N * __builtin_amdgcn_rcpf(P * d);
    float Ec = fexp2(-2.f * L2E * c);
    return (1.f - Ec) * __builtin_amdgcn_rcpf((1.f + Ec) * (1.f + Eo));
}

__global__ __launch_bounds__(512, 4)
void lstm2_fused(const float* __restrict__ x,
                 const float* __restrict__ wih0, const float* __restrict__ whh0,
                 const float* __restrict__ bih0, const float* __restrict__ bhh0,
                 const float* __restrict__ wih1, const float* __restrict__ whh1,
                 const float* __restrict__ bih1, const float* __restrict__ bhh1,
                 const float* __restrict__ fcw,  const float* __restrict__ fcb,
                 float* __restrict__ out)
{
    const int tid  = threadIdx.x;
    const int lane = tid & 63;
    const int wv   = tid >> 6;      // 0..7 -> h block 8*wv
    const int bl   = lane & 15;
    const int kg   = lane >> 4;

    __shared__ alignas(16) unsigned short hb[2][2][BT * 64];  // layer,parity,[b][h] f16
    __shared__ float wpart[8][BT];

    for (int i = tid; i < (int)(sizeof(hb) / 4); i += 512) ((int*)hb)[i] = 0;

    // ---- weights: gate-interleaved row tiles, log2e folded ----
    h8 W0[2][3], W1[2][4];
    f4 b0v[2], b1v[2];
    #pragma unroll
    for (int t = 0; t < 2; ++t) {
        const int hbse = 8 * wv + 4 * t;
        const int gam  = bl & 3;                         // gate of this A-row
        const int g    = 64 * gam + hbse + (bl >> 2);    // global weight row
        const float sc = (gam == 2) ? 2.f * L2E : L2E;
        W0[t][0] = cvt8s(wih0 + g * 32 + 8 * kg, sc);
        W0[t][1] = cvt8s(whh0 + g * 64 + 8 * kg, sc);
        W0[t][2] = cvt8s(whh0 + g * 64 + 32 + 8 * kg, sc);
        W1[t][0] = cvt8s(wih1 + g * 64 + 8 * kg, sc);
        W1[t][1] = cvt8s(wih1 + g * 64 + 32 + 8 * kg, sc);
        W1[t][2] = cvt8s(whh1 + g * 64 + 8 * kg, sc);
        W1[t][3] = cvt8s(whh1 + g * 64 + 32 + 8 * kg, sc);
        #pragma unroll
        for (int r = 0; r < 4; ++r) {
            const int gr = 64 * r + hbse + kg;           // D element r = gate r of h=hbse+kg
            const float scr = (r == 2) ? 2.f * L2E : L2E;
            b0v[t][r] = (bih0[gr] + bhh0[gr]) * scr;
            b1v[t][r] = (bih1[gr] + bhh1[gr]) * scr;
        }
    }

    const int bbase = blockIdx.x * BT;
    const float* xp = x + (size_t)(bbase + bl) * (TT * DIN) + 8 * kg;

    float c0[2] = {0.f, 0.f}, c1[2] = {0.f, 0.f}, h1f[2] = {0.f, 0.f};

    __syncthreads();   // LDS zero visible

    const int swz = (bl & 7) << 4;
    char* lb = (char*)hb;
    const int rowoff = bl * 128;
    const int rd0 = rowoff + ((16 * kg) ^ swz);
    const int rd1 = rowoff + ((64 + 16 * kg) ^ swz);
    const int wro0 = rowoff + ((16 * wv + 2 * kg) ^ swz);        // h = 8wv+kg   (t=0)
    const int wro1 = rowoff + ((16 * wv + 8 + 2 * kg) ^ swz);    // h = 8wv+4+kg (t=1)

    auto L0 = [&](const h8& xc, const h8& hr0, const h8& hr1, int wp) {
        #pragma unroll
        for (int t = 0; t < 2; ++t) {
            f4 acc = b0v[t];
            acc = __builtin_amdgcn_mfma_f32_16x16x32_f16(W0[t][1], hr0, acc, 0, 0, 0);
            acc = __builtin_amdgcn_mfma_f32_16x16x32_f16(W0[t][2], hr1, acc, 0, 0, 0);
            acc = __builtin_amdgcn_mfma_f32_16x16x32_f16(W0[t][0], xc,  acc, 0, 0, 0);
            float h = elem(acc, c0[t]);
            *(_Float16*)(lb + wp * 2048 + (t ? wro1 : wro0)) = (_Float16)h;
        }
    };

    auto L1 = [&](const h8& g0a, const h8& g0b, const h8& g1a, const h8& g1b,
                  int wp, bool store) {
        #pragma unroll
        for (int t = 0; t < 2; ++t) {
            f4 acc = b1v[t];
            acc = __builtin_amdgcn_mfma_f32_16x16x32_f16(W1[t][0], g0a, acc, 0, 0, 0);
            acc = __builtin_amdgcn_mfma_f32_16x16x32_f16(W1[t][1], g0b, acc, 0, 0, 0);
            acc = __builtin_amdgcn_mfma_f32_16x16x32_f16(W1[t][2], g1a, acc, 0, 0, 0);
            acc = __builtin_amdgcn_mfma_f32_16x16x32_f16(W1[t][3], g1b, acc, 0, 0, 0);
            float h = elem(acc, c1[t]);
            h1f[t] = h;
            if (store) *(_Float16*)(lb + 4096 + wp * 2048 + (t ? wro1 : wro0)) = (_Float16)h;
        }
    };

    h8 xcur;
    // ---- it = 0: L0 only (t=0); h0[-1]=0 from zeroed parity-1 buffer ----
    {
        float4 x0a = *(const float4*)(xp);
        float4 x0b = *(const float4*)(xp + 4);
        // prefetch x[1] before compute
        float4 xnA = *(const float4*)(xp + DIN);
        float4 xnB = *(const float4*)(xp + DIN + 4);
        h8 xc  = pack8(x0a, x0b);
        h8 hr0 = *(const h8*)(lb + 2048 + rd0);
        h8 hr1 = *(const h8*)(lb + 2048 + rd1);
        L0(xc, hr0, hr1, 0);
        xcur = pack8(xnA, xnB);
        __syncthreads();
    }

    // ---- it = 1..TT-1: L0(t=it) + L1(t=it-1), one barrier, x prefetched ----
    for (int it = 1; it < TT; ++it) {
        const int wp = it & 1, rp = wp ^ 1;
        // issue next-iter x loads FIRST (in flight across the whole body)
        const int tn = (it + 1 < TT) ? it + 1 : TT - 1;
        float4 xnA = *(const float4*)(xp + tn * DIN);
        float4 xnB = *(const float4*)(xp + tn * DIN + 4);

        h8 hr0 = *(const h8*)(lb + rp * 2048 + rd0);          // h0[it-1]
        h8 hr1 = *(const h8*)(lb + rp * 2048 + rd1);
        h8 g1a = *(const h8*)(lb + 4096 + rp * 2048 + rd0);   // h1[it-2]
        h8 g1b = *(const h8*)(lb + 4096 + rp * 2048 + rd1);

        L0(xcur, hr0, hr1, wp);
        L1(hr0, hr1, g1a, g1b, wp, true);

        xcur = pack8(xnA, xnB);   // vmcnt wait lands here, after all compute
        __syncthreads();
    }

    // ---- tail: L1 for t = TT-1 ----
    {
        const int rp = 1;   // TT even: last write parity
        h8 hr0 = *(const h8*)(lb + rp * 2048 + rd0);          // h0[TT-1]
        h8 hr1 = *(const h8*)(lb + rp * 2048 + rd1);
        h8 g1a = *(const h8*)(lb + 4096 + rp * 2048 + rd0);   // h1[TT-2]
        h8 g1b = *(const h8*)(lb + 4096 + rp * 2048 + rd1);
        L1(hr0, hr1, g1a, g1b, 0, false);
    }

    // ---- head: out[b] = h1 . fc_w + fc_b ----
    float part = h1f[0] * fcw[8 * wv + kg] + h1f[1] * fcw[8 * wv + 4 + kg];
    part += __shfl_xor(part, 16, 64);
    part += __shfl_xor(part, 32, 64);
    if (lane < 16) wpart[wv][lane] = part;
    __syncthreads();
    if (tid < BT) {
        float s = fcb[0];
        #pragma unroll
        for (int w = 0; w < 8; ++w) s += wpart[w][tid];
        out[bbase + tid] = s;
    }
}

extern "C" void kernel_launch(void* const* d_in, const int* in_sizes, int n_in,
                              void* d_out, int out_size, void* d_ws, size_t ws_size,
                              hipStream_t stream) {
    (void)in_sizes; (void)n_in; (void)d_ws; (void)ws_size; (void)out_size;
    lstm2_fused<<<dim3(8192 / BT), dim3(512), 0, stream>>>(
        (const float*)d_in[0],
        (const float*)d_in[1], (const float*)d_in[2],
        (const float*)d_in[3], (const float*)d_in[4],
        (const float*)d_in[5], (const float*)d_in[6],
        (const float*)d_in[7], (const float*)d_in[8],
        (const float*)d_in[9], (const float*)d_in[10],
        (float*)d_out);
}

// Round 9
// 184.960 us; speedup vs baseline: 1.4900x; 1.4900x over previous
//
#include <hip/hip_runtime.h>

// 2-layer fused LSTM + linear head.  B=8192, T=128, D=32, H=64, gates=256.
// R9 = R6 (512 thr / 8 waves, BT=16, grid 512, 1 barrier/step, x prefetch,
// hw exp2 - poly reverted, R8 proved hw trans ~13-16cy < poly ~22cy) plus:
//  - all 14 MFMAs per step issued as ONE cluster before any elem VALU
//    (lets the MFMA-pipe arbiter stagger waves; VALU pipe then runs
//    continuously across waves instead of phase-locked bursts)
//  - s_setprio(1) around the MFMA cluster (T5, role diversity exists here)
//  - 2x unroll + last-iter peel: parity offsets become literals
// Wave wv owns h in [8wv,8wv+8) as 2 gate-interleaved row-tiles:
//   D element r of lane (bl,kg) = gate r of h = hbase+kg (all 4 gates/lane).
// log2e folded into weights (i,f,o x1.4427; g x2.8854); merged-rcp gate math:
//   5 exp2 + 2 rcp = 7 trans/element.

#define TT  128
#define DIN 32
#define BT  16
#define L2E 1.44269504088896340736f

typedef _Float16 h8 __attribute__((ext_vector_type(8)));
typedef __fp16   p2 __attribute__((ext_vector_type(2)));
typedef float    f4 __attribute__((ext_vector_type(4)));

#define MFMA(A, B, C) __builtin_amdgcn_mfma_f32_16x16x32_f16((A), (B), (C), 0, 0, 0)

__device__ __forceinline__ h8 cvt8s(const float* p, float s) {
    float4 a = *(const float4*)p;
    float4 b = *(const float4*)(p + 4);
    union { h8 v; p2 q[4]; } u;
    u.q[0] = __builtin_amdgcn_cvt_pkrtz(a.x * s, a.y * s);
    u.q[1] = __builtin_amdgcn_cvt_pkrtz(a.z * s, a.w * s);
    u.q[2] = __builtin_amdgcn_cvt_pkrtz(b.x * s, b.y * s);
    u.q[3] = __builtin_amdgcn_cvt_pkrtz(b.z * s, b.w * s);
    return u.v;
}

__device__ __forceinline__ h8 pack8(const float4& a, const float4& b) {
    union { h8 v; p2 q[4]; } u;
    u.q[0] = __builtin_amdgcn_cvt_pkrtz(a.x, a.y);
    u.q[1] = __builtin_amdgcn_cvt_pkrtz(a.z, a.w);
    u.q[2] = __builtin_amdgcn_cvt_pkrtz(b.x, b.y);
    u.q[3] = __builtin_amdgcn_cvt_pkrtz(b.z, b.w);
    return u.v;
}

// acc = {yi', yf', yg'(2x-scaled), yo'} (log2e pre-folded); updates c, returns h.
__device__ __forceinline__ float elem(const f4& acc, float& c) {
    float Ei = __builtin_amdgcn_exp2f(-acc[0]);
    float Ef = __builtin_amdgcn_exp2f(-acc[1]);
    float Eg = __builtin_amdgcn_exp2f(-acc[2]);
    float Eo = __builtin_amdgcn_exp2f(-acc[3]);
    float a = 1.f + Ei, b = 1.f + Eg, d = 1.f + Ef;
    float P = a * b;
    float N = c * P + (1.f - Eg) * d;
    c = N * __builtin_amdgcn_rcpf(P * d);
    float Ec = __builtin_amdgcn_exp2f(-2.f * L2E * c);
    return (1.f - Ec) * __builtin_amdgcn_rcpf((1.f + Ec) * (1.f + Eo));
}

__global__ __launch_bounds__(512, 4)
void lstm2_fused(const float* __restrict__ x,
                 const float* __restrict__ wih0, const float* __restrict__ whh0,
                 const float* __restrict__ bih0, const float* __restrict__ bhh0,
                 const float* __restrict__ wih1, const float* __restrict__ whh1,
                 const float* __restrict__ bih1, const float* __restrict__ bhh1,
                 const float* __restrict__ fcw,  const float* __restrict__ fcb,
                 float* __restrict__ out)
{
    const int tid  = threadIdx.x;
    const int lane = tid & 63;
    const int wv   = tid >> 6;      // 0..7 -> h block 8*wv
    const int bl   = lane & 15;
    const int kg   = lane >> 4;

    __shared__ alignas(16) unsigned short hb[2][2][BT * 64];  // layer,parity,[b][h] f16
    __shared__ float wpart[8][BT];

    for (int i = tid; i < (int)(sizeof(hb) / 4); i += 512) ((int*)hb)[i] = 0;

    // ---- weights: gate-interleaved row tiles, log2e folded ----
    h8 W0[2][3], W1[2][4];
    f4 b0v[2], b1v[2];
    #pragma unroll
    for (int t = 0; t < 2; ++t) {
        const int hbse = 8 * wv + 4 * t;
        const int gam  = bl & 3;                         // gate of this A-row
        const int g    = 64 * gam + hbse + (bl >> 2);    // global weight row
        const float sc = (gam == 2) ? 2.f * L2E : L2E;
        W0[t][0] = cvt8s(wih0 + g * 32 + 8 * kg, sc);
        W0[t][1] = cvt8s(whh0 + g * 64 + 8 * kg, sc);
        W0[t][2] = cvt8s(whh0 + g * 64 + 32 + 8 * kg, sc);
        W1[t][0] = cvt8s(wih1 + g * 64 + 8 * kg, sc);
        W1[t][1] = cvt8s(wih1 + g * 64 + 32 + 8 * kg, sc);
        W1[t][2] = cvt8s(whh1 + g * 64 + 8 * kg, sc);
        W1[t][3] = cvt8s(whh1 + g * 64 + 32 + 8 * kg, sc);
        #pragma unroll
        for (int r = 0; r < 4; ++r) {
            const int gr = 64 * r + hbse + kg;           // D element r = gate r of h=hbse+kg
            const float scr = (r == 2) ? 2.f * L2E : L2E;
            b0v[t][r] = (bih0[gr] + bhh0[gr]) * scr;
            b1v[t][r] = (bih1[gr] + bhh1[gr]) * scr;
        }
    }

    const int bbase = blockIdx.x * BT;
    const float* xp = x + (size_t)(bbase + bl) * (TT * DIN) + 8 * kg;

    float c0[2] = {0.f, 0.f}, c1[2] = {0.f, 0.f}, h1f[2] = {0.f, 0.f};

    __syncthreads();   // LDS zero visible

    const int swz = (bl & 7) << 4;
    char* lb = (char*)hb;
    const int rowoff = bl * 128;
    const int rd0 = rowoff + ((16 * kg) ^ swz);
    const int rd1 = rowoff + ((64 + 16 * kg) ^ swz);
    const int wro0 = rowoff + ((16 * wv + 2 * kg) ^ swz);        // h = 8wv+kg   (t=0)
    const int wro1 = rowoff + ((16 * wv + 8 + 2 * kg) ^ swz);    // h = 8wv+4+kg (t=1)

    h8 xcur;

    // One skewed step: {L0[it], L1[it-1]} with MFMA cluster first, then elems.
    // wp/rp become literals at each call site (2x unroll + peel).
    auto STEP = [&](int wp, int rp, const float* xnext) {
        float4 xnA, xnB;
        if (xnext) { xnA = *(const float4*)xnext; xnB = *(const float4*)(xnext + 4); }

        h8 hr0 = *(const h8*)(lb + rp * 2048 + rd0);          // h0[it-1]
        h8 hr1 = *(const h8*)(lb + rp * 2048 + rd1);
        h8 g1a = *(const h8*)(lb + 4096 + rp * 2048 + rd0);   // h1[it-2]
        h8 g1b = *(const h8*)(lb + 4096 + rp * 2048 + rd1);

        __builtin_amdgcn_s_setprio(1);
        f4 a00 = b0v[0];
        a00 = MFMA(W0[0][1], hr0, a00);
        a00 = MFMA(W0[0][2], hr1, a00);
        a00 = MFMA(W0[0][0], xcur, a00);
        f4 a01 = b0v[1];
        a01 = MFMA(W0[1][1], hr0, a01);
        a01 = MFMA(W0[1][2], hr1, a01);
        a01 = MFMA(W0[1][0], xcur, a01);
        f4 a10 = b1v[0];
        a10 = MFMA(W1[0][0], hr0, a10);
        a10 = MFMA(W1[0][1], hr1, a10);
        a10 = MFMA(W1[0][2], g1a, a10);
        a10 = MFMA(W1[0][3], g1b, a10);
        f4 a11 = b1v[1];
        a11 = MFMA(W1[1][0], hr0, a11);
        a11 = MFMA(W1[1][1], hr1, a11);
        a11 = MFMA(W1[1][2], g1a, a11);
        a11 = MFMA(W1[1][3], g1b, a11);
        __builtin_amdgcn_s_setprio(0);

        float h00 = elem(a00, c0[0]);
        float h01 = elem(a01, c0[1]);
        float h10 = elem(a10, c1[0]);
        float h11 = elem(a11, c1[1]);
        h1f[0] = h10; h1f[1] = h11;

        *(_Float16*)(lb + wp * 2048 + wro0) = (_Float16)h00;
        *(_Float16*)(lb + wp * 2048 + wro1) = (_Float16)h01;
        *(_Float16*)(lb + 4096 + wp * 2048 + wro0) = (_Float16)h10;
        *(_Float16*)(lb + 4096 + wp * 2048 + wro1) = (_Float16)h11;

        if (xnext) xcur = pack8(xnA, xnB);
        __syncthreads();
    };

    // ---- it = 0: L0 only (t=0); h0[-1]=0 from zeroed parity-1 buffer ----
    {
        float4 x0a = *(const float4*)(xp);
        float4 x0b = *(const float4*)(xp + 4);
        float4 xnA = *(const float4*)(xp + DIN);       // prefetch x[1]
        float4 xnB = *(const float4*)(xp + DIN + 4);
        h8 xc  = pack8(x0a, x0b);
        h8 hr0 = *(const h8*)(lb + 2048 + rd0);
        h8 hr1 = *(const h8*)(lb + 2048 + rd1);
        __builtin_amdgcn_s_setprio(1);
        f4 a00 = b0v[0];
        a00 = MFMA(W0[0][1], hr0, a00);
        a00 = MFMA(W0[0][2], hr1, a00);
        a00 = MFMA(W0[0][0], xc, a00);
        f4 a01 = b0v[1];
        a01 = MFMA(W0[1][1], hr0, a01);
        a01 = MFMA(W0[1][2], hr1, a01);
        a01 = MFMA(W0[1][0], xc, a01);
        __builtin_amdgcn_s_setprio(0);
        float h00 = elem(a00, c0[0]);
        float h01 = elem(a01, c0[1]);
        *(_Float16*)(lb + 0 * 2048 + wro0) = (_Float16)h00;
        *(_Float16*)(lb + 0 * 2048 + wro1) = (_Float16)h01;
        xcur = pack8(xnA, xnB);
        __syncthreads();
    }

    // ---- it = 1..126 unrolled x2 (parities literal), then peel it=127 ----
    for (int itp = 1; itp < TT - 1; itp += 2) {
        STEP(1, 0, xp + (itp + 1) * DIN);   // it = itp   (odd)
        STEP(0, 1, xp + (itp + 2) * DIN);   // it = itp+1 (even)
    }
    STEP(1, 0, nullptr);                    // it = 127

    // ---- tail: L1 for t = TT-1 (reads parity 1) ----
    {
        h8 hr0 = *(const h8*)(lb + 2048 + rd0);              // h0[127]
        h8 hr1 = *(const h8*)(lb + 2048 + rd1);
        h8 g1a = *(const h8*)(lb + 4096 + 2048 + rd0);       // h1[126]
        h8 g1b = *(const h8*)(lb + 4096 + 2048 + rd1);
        #pragma unroll
        for (int t = 0; t < 2; ++t) {
            f4 acc = b1v[t];
            acc = MFMA(W1[t][0], hr0, acc);
            acc = MFMA(W1[t][1], hr1, acc);
            acc = MFMA(W1[t][2], g1a, acc);
            acc = MFMA(W1[t][3], g1b, acc);
            h1f[t] = elem(acc, c1[t]);
        }
    }

    // ---- head: out[b] = h1 . fc_w + fc_b ----
    float part = h1f[0] * fcw[8 * wv + kg] + h1f[1] * fcw[8 * wv + 4 + kg];
    part += __shfl_xor(part, 16, 64);
    part += __shfl_xor(part, 32, 64);
    if (lane < 16) wpart[wv][lane] = part;
    __syncthreads();
    if (tid < BT) {
        float s = fcb[0];
        #pragma unroll
        for (int w = 0; w < 8; ++w) s += wpart[w][tid];
        out[bbase + tid] = s;
    }
}

extern "C" void kernel_launch(void* const* d_in, const int* in_sizes, int n_in,
                              void* d_out, int out_size, void* d_ws, size_t ws_size,
                              hipStream_t stream) {
    (void)in_sizes; (void)n_in; (void)d_ws; (void)ws_size; (void)out_size;
    lstm2_fused<<<dim3(8192 / BT), dim3(512), 0, stream>>>(
        (const float*)d_in[0],
        (const float*)d_in[1], (const float*)d_in[2],
        (const float*)d_in[3], (const float*)d_in[4],
        (const float*)d_in[5], (const float*)d_in[6],
        (const float*)d_in[7], (const float*)d_in[8],
        (const float*)d_in[9], (const float*)d_in[10],
        (float*)d_out);
}